// Round 1
// baseline (1200.613 us; speedup 1.0000x reference)
//
#include <hip/hip_runtime.h>

#define NA 8192
#define NB 8192
#define N_LAYERS 16
#define ROWS_PER_RC 128
#define N_RC (NA / ROWS_PER_RC) // 64

typedef _Float16 half_t;
typedef _Float16 half4_t __attribute__((ext_vector_type(4)));
typedef _Float16 half8_t __attribute__((ext_vector_type(8)));
typedef float float4_t __attribute__((ext_vector_type(4)));

// ---------------------------------------------------------------------------
// Layer-1 u-update fused with C(fp32) -> E=exp(-C/eps) (fp16) conversion.
// v == 1 implicitly (g starts at 0). Block-per-row, 256 threads.
// ---------------------------------------------------------------------------
template <bool WRITE_E>
__global__ __launch_bounds__(256) void sink_u_first(
    const float* __restrict__ C, const float* __restrict__ alpha,
    const float* __restrict__ d_eps, half_t* __restrict__ E,
    float* __restrict__ u)
{
    const int row = blockIdx.x;
    const int t = threadIdx.x;
    const float inv_eps = 1.0f / d_eps[0];
    const float4_t* Crow = (const float4_t*)(C + (size_t)row * NB);
    half4_t* Erow = (half4_t*)(E + (size_t)row * NB);

    float s = 0.0f;
#pragma unroll
    for (int k = 0; k < 8; ++k) {
        const int idx = k * 256 + t;            // float4 group, 2048 per row
        float4_t c = Crow[idx];
        float e0 = __expf(-c.x * inv_eps);
        float e1 = __expf(-c.y * inv_eps);
        float e2 = __expf(-c.z * inv_eps);
        float e3 = __expf(-c.w * inv_eps);
        if (WRITE_E) {
            half4_t h;
            h.x = (_Float16)e0; h.y = (_Float16)e1;
            h.z = (_Float16)e2; h.w = (_Float16)e3;
            Erow[idx] = h;
        }
        s += (e0 + e1) + (e2 + e3);
    }

    __shared__ float sm[256];
    sm[t] = s;
    __syncthreads();
    for (int off = 128; off > 0; off >>= 1) {
        if (t < off) sm[t] += sm[t + off];
        __syncthreads();
    }
    if (t == 0) u[row] = alpha[row] / sm[0];
}

// ---------------------------------------------------------------------------
// u-update, layers 2..16: u[i] = alpha[i] / sum_j E[i,j]*v[j].
// Block-per-row, 256 threads. USE_E: read fp16 E; else read fp32 C + expf.
// ---------------------------------------------------------------------------
template <bool USE_E>
__global__ __launch_bounds__(256) void sink_u_step(
    const void* __restrict__ mat, const float* __restrict__ v,
    const float* __restrict__ alpha, const float* __restrict__ d_eps,
    float* __restrict__ u)
{
    const int row = blockIdx.x;
    const int t = threadIdx.x;
    const float4_t* vv = (const float4_t*)v;
    float s = 0.0f;

    if (USE_E) {
        const half4_t* Erow = (const half4_t*)mat + (size_t)row * (NB / 4);
#pragma unroll
        for (int k = 0; k < 8; ++k) {
            const int idx = k * 256 + t;
            half4_t e = Erow[idx];
            float4_t w = vv[idx];
            s += (float)e.x * w.x + (float)e.y * w.y +
                 (float)e.z * w.z + (float)e.w * w.w;
        }
    } else {
        const float inv_eps = 1.0f / d_eps[0];
        const float4_t* Crow = (const float4_t*)mat + (size_t)row * (NB / 4);
#pragma unroll
        for (int k = 0; k < 8; ++k) {
            const int idx = k * 256 + t;
            float4_t c = Crow[idx];
            float4_t w = vv[idx];
            s += __expf(-c.x * inv_eps) * w.x + __expf(-c.y * inv_eps) * w.y +
                 __expf(-c.z * inv_eps) * w.z + __expf(-c.w * inv_eps) * w.w;
        }
    }

    __shared__ float sm[256];
    sm[t] = s;
    __syncthreads();
    for (int off = 128; off > 0; off >>= 1) {
        if (t < off) sm[t] += sm[t + off];
        __syncthreads();
    }
    if (t == 0) u[row] = alpha[row] / sm[0];
}

// ---------------------------------------------------------------------------
// v-update partial sums: partial[rc][j] = sum_{i in row-chunk rc} E[i,j]*u[i].
// Grid (4 col-chunks, 64 row-chunks) x 256 threads; thread owns 8 columns.
// Fully coalesced 16B/lane fp16 loads.
// ---------------------------------------------------------------------------
template <bool USE_E>
__global__ __launch_bounds__(256) void sink_v_partial(
    const void* __restrict__ mat, const float* __restrict__ u,
    const float* __restrict__ d_eps, float* __restrict__ partial)
{
    const int cc = blockIdx.x;  // 0..3
    const int rc = blockIdx.y;  // 0..63
    const int t = threadIdx.x;
    const int row0 = rc * ROWS_PER_RC;

    float acc[8];
#pragma unroll
    for (int k = 0; k < 8; ++k) acc[k] = 0.0f;

    if (USE_E) {
        const half8_t* Eb = (const half8_t*)mat;
        const int g = cc * 256 + t;  // half8 group; 1024 per row
#pragma unroll 4
        for (int r = 0; r < ROWS_PER_RC; ++r) {
            const float ur = u[row0 + r];
            half8_t e = Eb[(size_t)(row0 + r) * (NB / 8) + g];
#pragma unroll
            for (int k = 0; k < 8; ++k) acc[k] += ur * (float)e[k];
        }
    } else {
        const float inv_eps = 1.0f / d_eps[0];
        const float4_t* Cb = (const float4_t*)mat;
        const int g = (cc * 256 + t) * 2;  // float4 group; 2048 per row
#pragma unroll 2
        for (int r = 0; r < ROWS_PER_RC; ++r) {
            const float ur = u[row0 + r];
            float4_t c0 = Cb[(size_t)(row0 + r) * (NB / 4) + g];
            float4_t c1 = Cb[(size_t)(row0 + r) * (NB / 4) + g + 1];
            acc[0] += ur * __expf(-c0.x * inv_eps);
            acc[1] += ur * __expf(-c0.y * inv_eps);
            acc[2] += ur * __expf(-c0.z * inv_eps);
            acc[3] += ur * __expf(-c0.w * inv_eps);
            acc[4] += ur * __expf(-c1.x * inv_eps);
            acc[5] += ur * __expf(-c1.y * inv_eps);
            acc[6] += ur * __expf(-c1.z * inv_eps);
            acc[7] += ur * __expf(-c1.w * inv_eps);
        }
    }

    float4_t o0 = {acc[0], acc[1], acc[2], acc[3]};
    float4_t o1 = {acc[4], acc[5], acc[6], acc[7]};
    float4_t* p = (float4_t*)(partial + (size_t)rc * NB + (size_t)(cc * 256 + t) * 8);
    p[0] = o0;
    p[1] = o1;
}

// ---------------------------------------------------------------------------
// v-update combine: v[j] = beta[j] / sum_rc partial[rc][j].
// ---------------------------------------------------------------------------
__global__ __launch_bounds__(256) void sink_v_combine(
    const float* __restrict__ partial, const float* __restrict__ beta,
    float* __restrict__ v)
{
    const int col = blockIdx.x * 256 + threadIdx.x;
    float s = 0.0f;
#pragma unroll 8
    for (int rc = 0; rc < N_RC; ++rc) s += partial[(size_t)rc * NB + col];
    v[col] = beta[col] / s;
}

// ---------------------------------------------------------------------------
// f = eps*log(u), g = eps*log(v), concatenated into d_out.
// ---------------------------------------------------------------------------
__global__ __launch_bounds__(256) void sink_finalize(
    const float* __restrict__ u, const float* __restrict__ v,
    const float* __restrict__ d_eps, float* __restrict__ out)
{
    const int i = blockIdx.x * 256 + threadIdx.x;
    const float eps = d_eps[0];
    if (i < NA) {
        out[i] = eps * logf(u[i]);
    } else if (i < NA + NB) {
        out[i] = eps * logf(v[i - NA]);
    }
}

extern "C" void kernel_launch(void* const* d_in, const int* in_sizes, int n_in,
                              void* d_out, int out_size, void* d_ws, size_t ws_size,
                              hipStream_t stream)
{
    const float* alpha = (const float*)d_in[0];
    const float* beta  = (const float*)d_in[1];
    const float* C     = (const float*)d_in[2];
    const float* d_eps = (const float*)d_in[3];
    float* out = (float*)d_out;

    const size_t eBytes = (size_t)NA * NB * sizeof(half_t); // 128 MiB
    const size_t pBytes = (size_t)N_RC * NB * sizeof(float); // 2 MiB
    const size_t vecBytes = (size_t)NA * sizeof(float);      // 32 KiB

    char* ws = (char*)d_ws;
    const bool useE = ws_size >= eBytes + pBytes + 2 * vecBytes;

    size_t off = 0;
    half_t* E = nullptr;
    if (useE) { E = (half_t*)ws; off += eBytes; }
    float* partial = (float*)(ws + off); off += pBytes;
    float* u = (float*)(ws + off); off += vecBytes;
    float* v = (float*)(ws + off); off += vecBytes;

    const dim3 blk(256);
    const dim3 gridRow(NA);
    const dim3 gridVP(NB / 2048, N_RC);
    const dim3 gridVC(NB / 256);

    for (int layer = 0; layer < N_LAYERS; ++layer) {
        if (layer == 0) {
            if (useE)
                sink_u_first<true><<<gridRow, blk, 0, stream>>>(C, alpha, d_eps, E, u);
            else
                sink_u_first<false><<<gridRow, blk, 0, stream>>>(C, alpha, d_eps, nullptr, u);
        } else {
            if (useE)
                sink_u_step<true><<<gridRow, blk, 0, stream>>>(E, v, alpha, d_eps, u);
            else
                sink_u_step<false><<<gridRow, blk, 0, stream>>>(C, v, alpha, d_eps, u);
        }
        if (useE)
            sink_v_partial<true><<<gridVP, blk, 0, stream>>>(E, u, d_eps, partial);
        else
            sink_v_partial<false><<<gridVP, blk, 0, stream>>>(C, u, d_eps, partial);
        sink_v_combine<<<gridVC, blk, 0, stream>>>(partial, beta, v);
    }
    sink_finalize<<<dim3((NA + NB) / 256), blk, 0, stream>>>(u, v, d_eps, out);
}